// Round 3
// baseline (223.261 us; speedup 1.0000x reference)
//
#include <hip/hip_runtime.h>
#include <hip/hip_cooperative_groups.h>

namespace cg = cooperative_groups;

// BiPointNet fully fused: 3x (binary 1x1 conv + BN batch-stats + ReLU) + maxpool.
// One cooperative kernel; masks live in registers/LDS; 3 grid.sync() for BN stats.
// B=8, N=1024, K=32 -> 262144 positions; channels 64->64->64->128.

typedef unsigned long long u64;

#define P_TOTAL (8192 * 32)
#define NBLK 512
#define WAVES 4          // waves per block
#define POSW 128         // positions per wave

// assemble 16-bit slices (at bit sh) of 4 ballots into one 64-bit mask
#define ASM16(b0, b1, b2, b3, sh)                                              \
    ((((b0) >> (sh)) & 0xFFFFull) | ((((b1) >> (sh)) & 0xFFFFull) << 16) |     \
     ((((b2) >> (sh)) & 0xFFFFull) << 32) | ((((b3) >> (sh)) & 0xFFFFull) << 48))

__device__ __forceinline__ u64 sel4(u64 a0, u64 a1, u64 a2, u64 a3, int j) {
    u64 lo = (j & 1) ? a1 : a0;
    u64 hi = (j & 1) ? a3 : a2;
    return (j & 2) ? hi : lo;
}

// fold BN(batch stats)+scale+gamma+beta into v = sa*dot + sb (block-local LDS)
__device__ __forceinline__ void compute_params(const int* __restrict__ sd,
        const int* __restrict__ sq, const float* __restrict__ scale,
        const float* __restrict__ gamma, const float* __restrict__ beta,
        float* sa, float* sb, int C) {
    int t = threadIdx.x;
    if (t < C) {
        const double invN = 1.0 / (double)P_TOTAL;
        double m = (double)sd[t] * invN;
        double var = (double)sq[t] * invN - m * m;
        double sc = (double)scale[t];
        double inv = 1.0 / sqrt(sc * sc * var + 1e-5);
        double g = (double)gamma[t];
        sa[t] = (float)(g * inv * sc);
        sb[t] = (float)((double)beta[t] - g * inv * sc * m);
    }
    __syncthreads();
}

__global__ void k_zero(int* __restrict__ stats) { stats[threadIdx.x] = 0; }

__global__ void __launch_bounds__(256, 2) kmain(
    const float4* __restrict__ in4,
    const float* __restrict__ W1, const float* __restrict__ s1,
    const float* __restrict__ g1, const float* __restrict__ b1,
    const float* __restrict__ W2, const float* __restrict__ s2,
    const float* __restrict__ g2, const float* __restrict__ b2,
    const float* __restrict__ W3, const float* __restrict__ s3,
    const float* __restrict__ g3, const float* __restrict__ b3,
    float* __restrict__ out, int* __restrict__ stats) {
    cg::grid_group grid = cg::this_grid();
    const int lane = threadIdx.x & 63;
    const int wib = threadIdx.x >> 6;
    const int wid = blockIdx.x * WAVES + wib;
    const int q_base = wid * POSW;

    __shared__ ulonglong2 ldsA1[WAVES][POSW];   // 8 KB: layer-1 input masks (perm order)
    __shared__ u64 ldsA2[WAVES][POSW];          // 4 KB: layer-1 output masks (natural)
    __shared__ float sa[128], sb[128];          // 1 KB: per-layer affine params
    __shared__ int rda[WAVES][64], rqa[WAVES][64], rdb[WAVES][64], rqb[WAVES][64]; // 4 KB

    // ---- pack weight masks via ballots (per wave, registers) ----
    u64 w1S = 0, w1N = 0, w2P = 0, w2N = 0, w3aP = 0, w3aN = 0, w3bP = 0, w3bN = 0;
    const int cperm = ((lane & 15) << 2) | (lane >> 4);   // inverse of k1 bit perm
    for (int q = 0; q < 64; ++q) {
        float w = W1[q * 64 + cperm];
        u64 bp = __ballot(w > 0.f), bn = __ballot(w != 0.f);
        if (lane == q) { w1S = bp; w1N = bn; }
    }
    for (int q = 0; q < 64; ++q) {
        float w = W2[q * 64 + lane];
        u64 bp = __ballot(w > 0.f), bn = __ballot(w < 0.f);
        if (lane == q) { w2P = bp; w2N = bn; }
    }
    for (int q = 0; q < 64; ++q) {
        float w = W3[q * 64 + lane];
        u64 bp = __ballot(w > 0.f), bn = __ballot(w < 0.f);
        if (lane == q) { w3aP = bp; w3aN = bn; }
    }
    for (int q = 0; q < 64; ++q) {
        float w = W3[(q + 64) * 64 + lane];
        u64 bp = __ballot(w > 0.f), bn = __ballot(w < 0.f);
        if (lane == q) { w3bP = bp; w3bN = bn; }
    }

    // ---- phase 1: stream input, ballot-pack A1 masks, layer-1 dot stats ----
    int sd = 0, sq = 0;
    for (int b = 0; b < 32; ++b) {
        const int q0 = q_base + b * 4;
        float4 v = in4[(size_t)q0 * 16 + lane];           // 1 KB contiguous per wave
        u64 bs0 = __ballot(v.x > 0.f), bn0 = __ballot(v.x != 0.f);
        u64 bs1 = __ballot(v.y > 0.f), bn1 = __ballot(v.y != 0.f);
        u64 bs2 = __ballot(v.z > 0.f), bn2 = __ballot(v.z != 0.f);
        u64 bs3 = __ballot(v.w > 0.f), bn3 = __ballot(v.w != 0.f);
        u64 as0 = ASM16(bs0, bs1, bs2, bs3, 0),  an0 = ASM16(bn0, bn1, bn2, bn3, 0);
        u64 as1 = ASM16(bs0, bs1, bs2, bs3, 16), an1 = ASM16(bn0, bn1, bn2, bn3, 16);
        u64 as2 = ASM16(bs0, bs1, bs2, bs3, 32), an2 = ASM16(bn0, bn1, bn2, bn3, 32);
        u64 as3 = ASM16(bs0, bs1, bs2, bs3, 48), an3 = ASM16(bn0, bn1, bn2, bn3, 48);
        {
            u64 mnz = an0 & w1N; int d = __popcll(mnz) - 2 * __popcll(mnz & (as0 ^ w1S));
            sd += d; sq += d * d;
        }
        {
            u64 mnz = an1 & w1N; int d = __popcll(mnz) - 2 * __popcll(mnz & (as1 ^ w1S));
            sd += d; sq += d * d;
        }
        {
            u64 mnz = an2 & w1N; int d = __popcll(mnz) - 2 * __popcll(mnz & (as2 ^ w1S));
            sd += d; sq += d * d;
        }
        {
            u64 mnz = an3 & w1N; int d = __popcll(mnz) - 2 * __popcll(mnz & (as3 ^ w1S));
            sd += d; sq += d * d;
        }
        if (lane < 4)
            ldsA1[wib][b * 4 + lane] =
                make_ulonglong2(sel4(as0, as1, as2, as3, lane), sel4(an0, an1, an2, an3, lane));
    }
    rda[wib][lane] = sd; rqa[wib][lane] = sq;
    __syncthreads();
    if (threadIdx.x < 64) {
        atomicAdd(&stats[lane],      rda[0][lane] + rda[1][lane] + rda[2][lane] + rda[3][lane]);
        atomicAdd(&stats[64 + lane], rqa[0][lane] + rqa[1][lane] + rqa[2][lane] + rqa[3][lane]);
    }
    grid.sync();
    compute_params(stats, stats + 64, s1, g1, b1, sa, sb, 64);

    // ---- phase 2: layer-1 binarize -> A2 masks (LDS), layer-2 dot stats ----
    const float a1 = sa[lane], bb1 = sb[lane];
    int sd2 = 0, sq2 = 0;
    #pragma unroll 4
    for (int p = 0; p < POSW; ++p) {
        ulonglong2 a = ldsA1[wib][p];                     // uniform addr: broadcast
        u64 mnz = a.y & w1N;
        int dot1 = __popcll(mnz) - 2 * __popcll(mnz & (a.x ^ w1S));
        float v = fmaf(a1, (float)dot1, bb1);
        u64 A = __ballot(v > 0.f);
        if (lane == 0) ldsA2[wib][p] = A;
        int d2 = __popcll(A & w2P) - __popcll(A & w2N);
        sd2 += d2; sq2 += d2 * d2;
    }
    rda[wib][lane] = sd2; rqa[wib][lane] = sq2;
    __syncthreads();
    if (threadIdx.x < 64) {
        atomicAdd(&stats[128 + lane], rda[0][lane] + rda[1][lane] + rda[2][lane] + rda[3][lane]);
        atomicAdd(&stats[192 + lane], rqa[0][lane] + rqa[1][lane] + rqa[2][lane] + rqa[3][lane]);
    }
    grid.sync();
    compute_params(stats + 128, stats + 192, s2, g2, b2, sa, sb, 64);

    // ---- phase 3: layer-2 binarize, layer-3 dots -> stats + per-row max/min ----
    const float a2 = sa[lane], bb2 = sb[lane];
    int sd3a = 0, sq3a = 0, sd3b = 0, sq3b = 0;
    int mxa[4], mna[4], mxb[4], mnb[4];
    #pragma unroll
    for (int r = 0; r < 4; ++r) {
        int xa = -127, na = 127, xb = -127, nb = 127;
        #pragma unroll 4
        for (int pp = 0; pp < 32; ++pp) {
            u64 A = ldsA2[wib][r * 32 + pp];              // uniform addr: broadcast
            int d2 = __popcll(A & w2P) - __popcll(A & w2N);
            float v = fmaf(a2, (float)d2, bb2);
            u64 A3 = __ballot(v > 0.f);
            int da = __popcll(A3 & w3aP) - __popcll(A3 & w3aN);
            int db = __popcll(A3 & w3bP) - __popcll(A3 & w3bN);
            sd3a += da; sq3a += da * da; sd3b += db; sq3b += db * db;
            xa = max(xa, da); na = min(na, da);
            xb = max(xb, db); nb = min(nb, db);
        }
        mxa[r] = xa; mna[r] = na; mxb[r] = xb; mnb[r] = nb;
    }
    rda[wib][lane] = sd3a; rqa[wib][lane] = sq3a;
    rdb[wib][lane] = sd3b; rqb[wib][lane] = sq3b;
    __syncthreads();
    if (threadIdx.x < 64) {
        atomicAdd(&stats[256 + lane],       rda[0][lane] + rda[1][lane] + rda[2][lane] + rda[3][lane]);
        atomicAdd(&stats[384 + lane],       rqa[0][lane] + rqa[1][lane] + rqa[2][lane] + rqa[3][lane]);
        atomicAdd(&stats[256 + 64 + lane],  rdb[0][lane] + rdb[1][lane] + rdb[2][lane] + rdb[3][lane]);
        atomicAdd(&stats[384 + 64 + lane],  rqb[0][lane] + rqb[1][lane] + rqb[2][lane] + rqb[3][lane]);
    }
    grid.sync();
    compute_params(stats + 256, stats + 384, s3, g3, b3, sa, sb, 128);

    // ---- phase 4: v = sa*(sa>=0?dmax:dmin)+sb, ReLU, write [8192,128] ----
    const float aa = sa[lane], ba = sb[lane];
    const float ab = sa[64 + lane], bbo = sb[64 + lane];
    #pragma unroll
    for (int r = 0; r < 4; ++r) {
        const int m = (q_base >> 5) + r;
        float va = fmaf(aa, (float)(aa >= 0.f ? mxa[r] : mna[r]), ba);
        float vb = fmaf(ab, (float)(ab >= 0.f ? mxb[r] : mnb[r]), bbo);
        out[(size_t)m * 128 + lane] = fmaxf(va, 0.f);
        out[(size_t)m * 128 + 64 + lane] = fmaxf(vb, 0.f);
    }
}

extern "C" void kernel_launch(void* const* d_in, const int* in_sizes, int n_in,
                              void* d_out, int out_size, void* d_ws, size_t ws_size,
                              hipStream_t stream) {
    const float4* in4 = (const float4*)d_in[0];
    const float* W1 = (const float*)d_in[1];
    const float* s1 = (const float*)d_in[2];
    const float* g1 = (const float*)d_in[3];
    const float* b1 = (const float*)d_in[4];
    const float* W2 = (const float*)d_in[5];
    const float* s2 = (const float*)d_in[6];
    const float* g2 = (const float*)d_in[7];
    const float* b2 = (const float*)d_in[8];
    const float* W3 = (const float*)d_in[9];
    const float* s3 = (const float*)d_in[10];
    const float* g3 = (const float*)d_in[11];
    const float* b3 = (const float*)d_in[12];
    float* out = (float*)d_out;
    int* stats = (int*)d_ws;   // 512 ints

    k_zero<<<1, 512, 0, stream>>>(stats);

    void* args[] = { (void*)&in4, (void*)&W1, (void*)&s1, (void*)&g1, (void*)&b1,
                     (void*)&W2, (void*)&s2, (void*)&g2, (void*)&b2,
                     (void*)&W3, (void*)&s3, (void*)&g3, (void*)&b3,
                     (void*)&out, (void*)&stats };
    hipLaunchCooperativeKernel((void*)kmain, dim3(NBLK), dim3(256), args, 0, stream);
}

// Round 4
// 98.250 us; speedup vs baseline: 2.2724x; 2.2724x over previous
//
#include <hip/hip_runtime.h>

// BiPointNet: 3x (binarized 1x1 conv + BN batch-stats + ReLU) + maxpool over K.
// 262144 positions; channels 64->64->64->128. Popcount-GEMM on 64-bit masks.
// v4: R2 5-kernel skeleton + (a) 2x waves for k2/k3 (4 waves/SIMD), (b) integer
// threshold binarize (fmaf(a,d,b)>0 <=> dot' >= T with sign-flipped masks for
// a<0) computed per-wave from stats -- exact same results as float path.

typedef unsigned long long u64;

#define P_TOTAL (8192 * 32)

__device__ __forceinline__ u64 bcast64(u64 x, int p) {
    unsigned lo = __builtin_amdgcn_readlane((unsigned)x, p);
    unsigned hi = __builtin_amdgcn_readlane((unsigned)(x >> 32), p);
    return ((u64)hi << 32) | lo;
}

// BN(batch stats)+scale+gamma+beta folded to v = a*dot + b for channel c
__device__ __forceinline__ void affine_from_stats(const int* __restrict__ sd,
        const int* __restrict__ sq, const float* __restrict__ scale,
        const float* __restrict__ gamma, const float* __restrict__ beta,
        int c, float& a, float& b) {
    const double invN = 1.0 / (double)P_TOTAL;
    double m = (double)sd[c] * invN;
    double var = (double)sq[c] * invN - m * m;
    double sc = (double)scale[c];
    double inv = 1.0 / sqrt(sc * sc * var + 1e-5);
    double g = (double)gamma[c];
    a = (float)(g * inv * sc);
    b = (float)((double)beta[c] - g * inv * sc * m);
}

// integer threshold T s.t. fmaf(a,(float)d,b)>0  <=>  d' >= T, where d' = dot
// (flip=false) or d' = -dot (flip=true). Exact: fma sign is exact; candidates
// verified by direct fmaf evaluation (monotone in d).
__device__ __forceinline__ int make_thresh(float a, float b, bool& flip) {
    if (a == 0.f) { flip = false; return (b > 0.f) ? -65 : 65; }
    double r = -(double)b / (double)a;
    r = fmin(fmax(r, -1e6), 1e6);
    int t0 = (int)floor(r);
    int T;
    if (a > 0.f) {
        flip = false;
        T = t0 + 2;
        if (fmaf(a, (float)(t0 + 1), b) > 0.f) T = t0 + 1;
        if (fmaf(a, (float)(t0    ), b) > 0.f) T = t0;
        if (fmaf(a, (float)(t0 - 1), b) > 0.f) T = t0 - 1;
    } else {
        flip = true;
        int H = t0 - 2;
        if (fmaf(a, (float)(t0 - 1), b) > 0.f) H = t0 - 1;
        if (fmaf(a, (float)(t0    ), b) > 0.f) H = t0;
        if (fmaf(a, (float)(t0 + 1), b) > 0.f) H = t0 + 1;
        T = -H;
    }
    return max(-65, min(65, T));
}

// ---------------- K0: pack weights into bitmasks, zero stats ----------------
// W1 packed with the k1 ballot permutation: channel c -> bit (c&3)*16 + (c>>2)
__global__ void k0_pack(const float* __restrict__ W1, const float* __restrict__ W2,
                        const float* __restrict__ W3,
                        ulonglong2* __restrict__ wp1, ulonglong2* __restrict__ wp2,
                        ulonglong2* __restrict__ wp3, int* __restrict__ stats) {
    int t = threadIdx.x;
    stats[t] = 0;
    stats[t + 256] = 0;
    if (t < 64) {
        u64 s = 0, nz = 0;
        for (int c = 0; c < 64; ++c) {
            float w = W1[t * 64 + c];
            int p = ((c & 3) << 4) | (c >> 2);
            if (w > 0.f) s |= 1ull << p;
            if (w != 0.f) nz |= 1ull << p;
        }
        wp1[t] = make_ulonglong2(s, nz);
    } else if (t < 128) {
        int o = t - 64;
        u64 pos = 0, neg = 0;
        for (int c = 0; c < 64; ++c) {
            float w = W2[o * 64 + c];
            if (w > 0.f) pos |= 1ull << c;
            if (w < 0.f) neg |= 1ull << c;
        }
        wp2[o] = make_ulonglong2(pos, neg);
    } else {
        int o = t - 128;
        u64 pos = 0, neg = 0;
        for (int c = 0; c < 64; ++c) {
            float w = W3[o * 64 + c];
            if (w > 0.f) pos |= 1ull << c;
            if (w < 0.f) neg |= 1ull << c;
        }
        wp3[o] = make_ulonglong2(pos, neg);
    }
}

// ------------- K1: float4 input pack (8 ballots / 4 positions) + L1 stats ----
__global__ void __launch_bounds__(256) k1_pack_stats(
    const float4* __restrict__ in4, const ulonglong2* __restrict__ wp1,
    ulonglong2* __restrict__ A1, int* __restrict__ sd_g, int* __restrict__ sq_g) {
    const int lane = threadIdx.x & 63;
    const int wib = threadIdx.x >> 6;
    const int wid = (blockIdx.x << 2) | wib;       // 4096 waves
    const ulonglong2 w = wp1[lane];                // permuted sign / nonzero
    const int sh = (lane >> 4) << 4;
    int sd = 0, sq = 0;
    for (int b = wid * 16, be = b + 16; b < be; ++b) {
        const int q0 = b << 2;
        float4 v = in4[(size_t)(q0 << 4) + lane];
        u64 bs0 = __ballot(v.x > 0.f), bn0 = __ballot(v.x != 0.f);
        u64 bs1 = __ballot(v.y > 0.f), bn1 = __ballot(v.y != 0.f);
        u64 bs2 = __ballot(v.z > 0.f), bn2 = __ballot(v.z != 0.f);
        u64 bs3 = __ballot(v.w > 0.f), bn3 = __ballot(v.w != 0.f);
        u64 myS = ((bs0 >> sh) & 0xFFFFull) | (((bs1 >> sh) & 0xFFFFull) << 16)
                | (((bs2 >> sh) & 0xFFFFull) << 32) | (((bs3 >> sh) & 0xFFFFull) << 48);
        u64 myN = ((bn0 >> sh) & 0xFFFFull) | (((bn1 >> sh) & 0xFFFFull) << 16)
                | (((bn2 >> sh) & 0xFFFFull) << 32) | (((bn3 >> sh) & 0xFFFFull) << 48);
        if ((lane & 15) == 0) A1[q0 + (lane >> 4)] = make_ulonglong2(myS, myN);
        #pragma unroll
        for (int p = 0; p < 4; ++p) {
            const int s2 = p << 4;
            u64 as = ((bs0 >> s2) & 0xFFFFull) | (((bs1 >> s2) & 0xFFFFull) << 16)
                   | (((bs2 >> s2) & 0xFFFFull) << 32) | (((bs3 >> s2) & 0xFFFFull) << 48);
            u64 an = ((bn0 >> s2) & 0xFFFFull) | (((bn1 >> s2) & 0xFFFFull) << 16)
                   | (((bn2 >> s2) & 0xFFFFull) << 32) | (((bn3 >> s2) & 0xFFFFull) << 48);
            u64 mnz = an & w.y;
            int dot = __popcll(mnz) - 2 * __popcll(mnz & (as ^ w.x));
            sd += dot; sq += dot * dot;
        }
    }
    __shared__ int rd[4][64], rq[4][64];
    rd[wib][lane] = sd; rq[wib][lane] = sq;
    __syncthreads();
    if (threadIdx.x < 64) {
        atomicAdd(&sd_g[lane], rd[0][lane] + rd[1][lane] + rd[2][lane] + rd[3][lane]);
        atomicAdd(&sq_g[lane], rq[0][lane] + rq[1][lane] + rq[2][lane] + rq[3][lane]);
    }
}

// -------- K2: layer-1 binarize (int thresh) -> A2, layer-2 dot stats --------
__global__ void __launch_bounds__(256, 4) k2_bin1_stats2(
    const ulonglong2* __restrict__ A1, const ulonglong2* __restrict__ wp1,
    const ulonglong2* __restrict__ wp2, const int* __restrict__ s1d,
    const int* __restrict__ s1q, const float* __restrict__ scale,
    const float* __restrict__ gamma, const float* __restrict__ beta,
    u64* __restrict__ A2, int* __restrict__ sd_g, int* __restrict__ sq_g) {
    const int lane = threadIdx.x & 63;
    const int wib = threadIdx.x >> 6;
    const int wid = (blockIdx.x << 2) | wib;       // 4096 waves x 64 positions
    float a, b;
    affine_from_stats(s1d, s1q, scale, gamma, beta, lane, a, b);
    bool flip;
    const int T = make_thresh(a, b, flip);
    ulonglong2 w1 = wp1[lane];
    const u64 w1S = flip ? ~w1.x : w1.x;           // flip => dot' = -dot
    const u64 w1N = w1.y;
    const ulonglong2 w2 = wp2[lane];               // natural orientation (stats)

    const int q0 = wid * 64;
    const ulonglong2 aa = A1[q0 + lane];           // coalesced 16B/lane
    u64 mymask = 0;
    int sd = 0, sq = 0;
    #pragma unroll 8
    for (int p = 0; p < 64; ++p) {
        u64 as = bcast64(aa.x, p);
        u64 an = bcast64(aa.y, p);
        u64 mnz = an & w1N;
        int dot1 = __popcll(mnz) - 2 * __popcll(mnz & (as ^ w1S));
        u64 A = __ballot(dot1 >= T);
        mymask = (lane == p) ? A : mymask;
        int d2 = __popcll(A & w2.x) - __popcll(A & w2.y);
        sd += d2; sq += d2 * d2;
    }
    A2[q0 + lane] = mymask;                        // coalesced 8B/lane

    __shared__ int rd[4][64], rq[4][64];
    rd[wib][lane] = sd; rq[wib][lane] = sq;
    __syncthreads();
    if (threadIdx.x < 64) {
        atomicAdd(&sd_g[lane], rd[0][lane] + rd[1][lane] + rd[2][lane] + rd[3][lane]);
        atomicAdd(&sq_g[lane], rq[0][lane] + rq[1][lane] + rq[2][lane] + rq[3][lane]);
    }
}

// -- K3: layer-2 binarize (int thresh), layer-3 dots -> stats + row max/min --
__global__ void __launch_bounds__(256, 4) k3_bin2_stats3(
    const u64* __restrict__ A2, const ulonglong2* __restrict__ wp2,
    const ulonglong2* __restrict__ wp3, const int* __restrict__ s2d,
    const int* __restrict__ s2q, const float* __restrict__ scale,
    const float* __restrict__ gamma, const float* __restrict__ beta,
    short* __restrict__ dmm, int* __restrict__ sd_g, int* __restrict__ sq_g) {
    const int lane = threadIdx.x & 63;
    const int wib = threadIdx.x >> 6;
    const int wid = (blockIdx.x << 2) | wib;       // 4096 waves x 64 pos (2 rows)
    float a, b;
    affine_from_stats(s2d, s2q, scale, gamma, beta, lane, a, b);
    bool flip;
    const int T = make_thresh(a, b, flip);
    const ulonglong2 w2 = wp2[lane];
    const u64 w2P = flip ? w2.y : w2.x;            // flip => swap pos/neg
    const u64 w2N = flip ? w2.x : w2.y;
    const ulonglong2 w3a = wp3[lane];
    const ulonglong2 w3b = wp3[lane + 64];

    const int q0 = wid * 64;
    const u64 aa = A2[q0 + lane];                  // coalesced 8B/lane
    int sda = 0, sqa = 0, sdb = 0, sqb = 0;
    #pragma unroll
    for (int r = 0; r < 2; ++r) {
        int maxa = -127, mina = 127, maxb = -127, minb = 127;
        #pragma unroll 8
        for (int pp = 0; pp < 32; ++pp) {
            const int p = (r << 5) | pp;
            u64 A = bcast64(aa, p);
            int d2 = __popcll(A & w2P) - __popcll(A & w2N);
            u64 A3 = __ballot(d2 >= T);
            int da = __popcll(A3 & w3a.x) - __popcll(A3 & w3a.y);
            int db = __popcll(A3 & w3b.x) - __popcll(A3 & w3b.y);
            sda += da; sqa += da * da; sdb += db; sqb += db * db;
            maxa = max(maxa, da); mina = min(mina, da);
            maxb = max(maxb, db); minb = min(minb, db);
        }
        const int m = (q0 >> 5) + r;
        dmm[m * 128 + lane]      = (short)((maxa & 0xFF) | ((mina & 0xFF) << 8));
        dmm[m * 128 + 64 + lane] = (short)((maxb & 0xFF) | ((minb & 0xFF) << 8));
    }
    __shared__ int rda[4][64], rqa[4][64], rdb[4][64], rqb[4][64];
    rda[wib][lane] = sda; rqa[wib][lane] = sqa;
    rdb[wib][lane] = sdb; rqb[wib][lane] = sqb;
    __syncthreads();
    if (threadIdx.x < 64) {
        atomicAdd(&sd_g[lane],      rda[0][lane] + rda[1][lane] + rda[2][lane] + rda[3][lane]);
        atomicAdd(&sq_g[lane],      rqa[0][lane] + rqa[1][lane] + rqa[2][lane] + rqa[3][lane]);
        atomicAdd(&sd_g[lane + 64], rdb[0][lane] + rdb[1][lane] + rdb[2][lane] + rdb[3][lane]);
        atomicAdd(&sq_g[lane + 64], rqb[0][lane] + rqb[1][lane] + rqb[2][lane] + rqb[3][lane]);
    }
}

// -------- K4: v = a*(a>=0?dmax:dmin)+b, ReLU, write [8192,128] --------------
__global__ void __launch_bounds__(256) k4_out(
    const short* __restrict__ dmm, const int* __restrict__ s3d,
    const int* __restrict__ s3q, const float* __restrict__ scale,
    const float* __restrict__ gamma, const float* __restrict__ beta,
    float* __restrict__ out) {
    __shared__ float sa[128], sb[128];
    if (threadIdx.x < 128)
        affine_from_stats(s3d, s3q, scale, gamma, beta, threadIdx.x,
                          sa[threadIdx.x], sb[threadIdx.x]);
    __syncthreads();
    const int idx = blockIdx.x * 256 + threadIdx.x;   // m*128 + o
    const int o = idx & 127;
    short pk = dmm[idx];
    int mx = (signed char)(pk & 0xFF);
    int mn = (signed char)((pk >> 8) & 0xFF);
    float a = sa[o], b = sb[o];
    float v = fmaf(a, (float)(a >= 0.f ? mx : mn), b);
    out[idx] = fmaxf(v, 0.f);
}

extern "C" void kernel_launch(void* const* d_in, const int* in_sizes, int n_in,
                              void* d_out, int out_size, void* d_ws, size_t ws_size,
                              hipStream_t stream) {
    const float* agg = (const float*)d_in[0];
    const float* W1 = (const float*)d_in[1];
    const float* s1 = (const float*)d_in[2];
    const float* g1 = (const float*)d_in[3];
    const float* b1 = (const float*)d_in[4];
    const float* W2 = (const float*)d_in[5];
    const float* s2 = (const float*)d_in[6];
    const float* g2 = (const float*)d_in[7];
    const float* b2 = (const float*)d_in[8];
    const float* W3 = (const float*)d_in[9];
    const float* s3 = (const float*)d_in[10];
    const float* g3 = (const float*)d_in[11];
    const float* b3 = (const float*)d_in[12];
    float* out = (float*)d_out;

    char* ws = (char*)d_ws;
    ulonglong2* wp1 = (ulonglong2*)(ws + 0);
    ulonglong2* wp2 = (ulonglong2*)(ws + 1024);
    ulonglong2* wp3 = (ulonglong2*)(ws + 2048);
    int* stats = (int*)(ws + 4096);                                    // 512 ints
    ulonglong2* A1 = (ulonglong2*)(ws + 8192);                         // 4 MB
    u64* A2 = (u64*)(ws + 8192 + (size_t)P_TOTAL * 16);                // 2 MB
    short* dmm = (short*)(ws + 8192 + (size_t)P_TOTAL * 24);           // 2 MB

    int* s1d = stats;        int* s1q = stats + 64;
    int* s2d = stats + 128;  int* s2q = stats + 192;
    int* s3d = stats + 256;  int* s3q = stats + 384;

    k0_pack<<<1, 256, 0, stream>>>(W1, W2, W3, wp1, wp2, wp3, stats);
    k1_pack_stats<<<1024, 256, 0, stream>>>((const float4*)agg, wp1, A1, s1d, s1q);
    k2_bin1_stats2<<<1024, 256, 0, stream>>>(A1, wp1, wp2, s1d, s1q, s1, g1, b1, A2, s2d, s2q);
    k3_bin2_stats3<<<1024, 256, 0, stream>>>(A2, wp2, wp3, s2d, s2q, s2, g2, b2, dmm, s3d, s3q);
    k4_out<<<4096, 256, 0, stream>>>(dmm, s3d, s3q, s3, g3, b3, out);
}